// Round 12
// baseline (573.339 us; speedup 1.0000x reference)
//
#include <hip/hip_runtime.h>

// NodeLevelSet: masked P2G scatter into a RANK-COMPACTED fixed-point
// accumulator (3.2 MB, L2-resident) + fused copy/friction epilogue.
//
// Rank trick: selected nodes are identified by a 256KB bitmask; a 256KB
// exclusive-scan table rankbase[] gives each selected node a dense slot:
//   slot = rankbase[id>>5] + popc(mask_word & ((1<<(id&31))-1))
// so the atomic target region is 2*u64*NS = 3.2MB instead of 33.6MB.
//
// Fixed-point packing (2 atomics per hit):
//   accA += [y_lane:32][x_lane:32]     lane = round(v*2^20) + 2^24
//   accB += [count:32][z_lane:32]      (1<<32) | z_lane
// Decode: v = (lane - count*2^24) * 2^-20. Lanes stay positive (bias 2^24),
// no cross-lane carries for count < ~100 (actual avg ~7.6).

#define MU_F 0.5f
#define SMALL_MASS_CUTOFF 1e-10f

#define FP_SCALE 1048576.0f              // 2^20
#define FP_INV   9.5367431640625e-07f    // 2^-20
#define FP_BIAS  (1 << 24)

typedef unsigned long long u64;
typedef unsigned int u32;

__device__ __forceinline__ u32 rank_of(int id, u32 mword,
                                       const u32* __restrict__ rankbase) {
    return rankbase[(u32)id >> 5] + __popc(mword & ((1u << (id & 31)) - 1u));
}

// ---- K1: set mask bits for selected nodes.
__global__ void mask_kernel(const int* __restrict__ id_stack, int ns,
                            u32* __restrict__ mask) {
    int i = blockIdx.x * blockDim.x + threadIdx.x;
    if (i >= ns) return;
    int id = id_stack[i];
    atomicOr(&mask[(u32)id >> 5], 1u << (id & 31));
}

// ---- K2: single-block exclusive scan of popcount(mask) -> rankbase.
__global__ void scan_kernel(const u32* __restrict__ mask,
                            u32* __restrict__ rankbase, int words) {
    __shared__ u32 wave_sums[16];
    const int t = threadIdx.x;           // blockDim.x == 1024
    const int per = (words + 1023) / 1024;
    const int w0 = t * per;
    const int w1 = (w0 + per < words) ? (w0 + per) : words;

    u32 local = 0;
    for (int w = w0; w < w1; ++w) local += __popc(mask[w]);

    // wave-64 inclusive scan
    u32 v = local;
    const int lane = t & 63;
    for (int d = 1; d < 64; d <<= 1) {
        u32 u = __shfl_up(v, d);
        if (lane >= d) v += u;
    }
    const int wid = t >> 6;
    if (lane == 63) wave_sums[wid] = v;
    __syncthreads();
    if (t == 0) {
        u32 run = 0;
        for (int i = 0; i < 16; ++i) { u32 s = wave_sums[i]; wave_sums[i] = run; run += s; }
    }
    __syncthreads();

    u32 excl = v - local + wave_sums[wid];   // exclusive prefix of this thread
    for (int w = w0; w < w1; ++w) {
        rankbase[w] = excl;
        excl += __popc(mask[w]);
    }
}

// ---- K3: zero compact acc records; repack velocity by rank.
__global__ void init_kernel(const int* __restrict__ id_stack,
                            const float* __restrict__ velocity,  // [NS,3]
                            const u32* __restrict__ mask,
                            const u32* __restrict__ rankbase,
                            u64* __restrict__ acc,
                            float* __restrict__ vel_r,           // [NS,3] by rank
                            int ns) {
    int i = blockIdx.x * blockDim.x + threadIdx.x;
    if (i >= ns) return;
    int id = id_stack[i];
    u32 mword = mask[(u32)id >> 5];
    u32 slot = rank_of(id, mword, rankbase);
    acc[2 * (size_t)slot]     = 0ull;
    acc[2 * (size_t)slot + 1] = 0ull;
    size_t sb = (size_t)slot * 3, ib = (size_t)i * 3;
    vel_r[sb + 0] = velocity[ib + 0];
    vel_r[sb + 1] = velocity[ib + 1];
    vel_r[sb + 2] = velocity[ib + 2];
}

// ---- K4: masked P2G. One thread per (particle, stencil-node) pair.
template <int LOG2W>
__global__ void p2g_kernel(const float* __restrict__ mass_stack,
                           const float* __restrict__ grad,   // [Np*W, 3]
                           const int*   __restrict__ ids,    // [Np*W]
                           const u32*   __restrict__ mask,
                           const u32*   __restrict__ rankbase,
                           u64* __restrict__ acc,
                           int npairs, int W) {
    int pair = blockIdx.x * blockDim.x + threadIdx.x;
    if (pair >= npairs) return;
    int id = ids[pair];                         // coalesced 4B/lane
    u32 mword = mask[(u32)id >> 5];             // 256KB, L2-hot
    if (mword & (1u << (id & 31))) {
        int pidx = (LOG2W > 0) ? (pair >> LOG2W) : (pair / W);
        float m = mass_stack[pidx];
        const float* g = grad + (size_t)pair * 3;
        int xi = __float2int_rn(g[0] * m * FP_SCALE);
        int yi = __float2int_rn(g[1] * m * FP_SCALE);
        int zi = __float2int_rn(g[2] * m * FP_SCALE);
        u64 a = ((u64)(u32)(yi + FP_BIAS) << 32) | (u32)(xi + FP_BIAS);
        u64 b = (1ull << 32) | (u32)(zi + FP_BIAS);
        u32 slot = rank_of(id, mword, rankbase);   // acc is 3.2MB: L2-resident
        atomicAdd(&acc[2 * (size_t)slot], a);
        atomicAdd(&acc[2 * (size_t)slot + 1], b);
    }
}

// ---- K5: fused epilogue over ALL nc nodes: copy-through or friction update.
__global__ void epilogue_kernel(const float* __restrict__ node_moment, // [NC,3]
                                const u32*   __restrict__ mask,
                                const u32*   __restrict__ rankbase,
                                const u64*   __restrict__ acc,
                                const float* __restrict__ node_mass,   // [NC]
                                const float* __restrict__ vel_r,       // [NS,3]
                                float* __restrict__ out,               // [NC,3]
                                int nc) {
    int c = blockIdx.x * blockDim.x + threadIdx.x;
    if (c >= nc) return;
    size_t b3 = (size_t)c * 3;
    float mx = node_moment[b3 + 0];
    float my = node_moment[b3 + 1];
    float mz = node_moment[b3 + 2];

    u32 mword = mask[(u32)c >> 5];
    if (!(mword & (1u << (c & 31)))) {          // untouched node: pass through
        out[b3 + 0] = mx; out[b3 + 1] = my; out[b3 + 2] = mz;
        return;
    }

    u32 slot = rank_of(c, mword, rankbase);
    u64 a  = acc[2 * (size_t)slot];
    u64 bb = acc[2 * (size_t)slot + 1];
    u32 cnt = (u32)(bb >> 32);
    long long bias = (long long)cnt << 24;
    float nx = (float)((long long)(a  & 0xFFFFFFFFull) - bias) * FP_INV;
    float ny = (float)((long long)(a  >> 32)           - bias) * FP_INV;
    float nz = (float)((long long)(bb & 0xFFFFFFFFull) - bias) * FP_INV;

    float mass = node_mass[c];
    bool valid = mass > SMALL_MASS_CUTOFF;
    float inv_mass = valid ? 1.0f / mass : 0.0f;
    float vx = mx * inv_mass, vy = my * inv_mass, vz = mz * inv_mass;

    float nn = sqrtf(nx * nx + ny * ny + nz * nz);
    bool ok = valid && (nn > 0.0f);
    float hx = 0.0f, hy = 0.0f, hz = 0.0f;
    if (ok) { float r = 1.0f / nn; hx = nx * r; hy = ny * r; hz = nz * r; }

    size_t sb = (size_t)slot * 3;
    float dvx = vx - vel_r[sb + 0];
    float dvy = vy - vel_r[sb + 1];
    float dvz = vz - vel_r[sb + 2];
    float dvn = dvx * hx + dvy * hy + dvz * hz;

    float ox = vx, oy = vy, oz = vz;
    if (dvn > 0.0f) {
        float cx = dvy * hz - dvz * hy;
        float cy = dvz * hx - dvx * hz;
        float cz = dvx * hy - dvy * hx;
        float cn = sqrtf(cx * cx + cy * cy + cz * cz);
        float wx = 0.0f, wy = 0.0f, wz = 0.0f;
        if (cn > 0.0f) { float r = 1.0f / cn; wx = cx * r; wy = cy * r; wz = cz * r; }
        float mu_p = fminf(MU_F, cn / dvn);
        float tx = hx + mu_p * (hy * wz - hz * wy);
        float ty = hy + mu_p * (hz * wx - hx * wz);
        float tz = hz + mu_p * (hx * wy - hy * wx);
        ox = vx - dvn * tx;
        oy = vy - dvn * ty;
        oz = vz - dvn * tz;
    }
    out[b3 + 0] = ox * mass;
    out[b3 + 1] = oy * mass;
    out[b3 + 2] = oz * mass;
}

extern "C" void kernel_launch(void* const* d_in, const int* in_sizes, int n_in,
                              void* d_out, int out_size, void* d_ws, size_t ws_size,
                              hipStream_t stream) {
    const float* mass_stack  = (const float*)d_in[0];
    const float* grad        = (const float*)d_in[1];
    const int*   cnode_ids   = (const int*)d_in[2];
    const float* node_moment = (const float*)d_in[3];
    const float* node_mass   = (const float*)d_in[4];
    const int*   id_stack    = (const int*)d_in[5];
    const float* velocity    = (const float*)d_in[6];
    float* out = (float*)d_out;

    const int np     = in_sizes[0];
    const int npairs = in_sizes[2];       // Np * W
    const int nc     = in_sizes[4];
    const int ns     = in_sizes[5];
    const int W      = npairs / np;
    const int words  = (nc + 31) / 32;

    // ws layout: acc u64[2*ns] | vel_r f32[3*ns] | mask u32[words] | rankbase u32[words]
    u64*   acc      = (u64*)d_ws;
    float* vel_r    = (float*)(acc + 2 * (size_t)ns);
    u32*   mask     = (u32*)(vel_r + 3 * (size_t)ns);
    u32*   rankbase = mask + (size_t)words;

    (void)hipMemsetAsync(mask, 0, (size_t)words * 4, stream);

    const int mb = (ns + 255) / 256;
    const int pb = (npairs + 255) / 256;
    const int eb = (nc + 255) / 256;

    mask_kernel<<<mb, 256, 0, stream>>>(id_stack, ns, mask);
    scan_kernel<<<1, 1024, 0, stream>>>(mask, rankbase, words);
    init_kernel<<<mb, 256, 0, stream>>>(id_stack, velocity, mask, rankbase,
                                        acc, vel_r, ns);
    if (W == 8)
        p2g_kernel<3><<<pb, 256, 0, stream>>>(mass_stack, grad, cnode_ids,
                                              mask, rankbase, acc, npairs, W);
    else if (W == 4)
        p2g_kernel<2><<<pb, 256, 0, stream>>>(mass_stack, grad, cnode_ids,
                                              mask, rankbase, acc, npairs, W);
    else
        p2g_kernel<0><<<pb, 256, 0, stream>>>(mass_stack, grad, cnode_ids,
                                              mask, rankbase, acc, npairs, W);
    epilogue_kernel<<<eb, 256, 0, stream>>>(node_moment, mask, rankbase, acc,
                                            node_mass, vel_r, out, nc);
}